// Round 3
// baseline (294.320 us; speedup 1.0000x reference)
//
#include <hip/hip_runtime.h>
#include <hip/hip_bf16.h>
#include <stdint.h>
#include <stddef.h>

// out[M,N] = X[M,K] @ sign(W[N,K])^T + bias[N];  M=N=K=4096, fp32 in/out.
#define M_DIM 4096
#define N_DIM 4096
#define K_DIM 4096
#define BM 256
#define BN 256
#define BK 64
#define NKT (K_DIM / BK)          // 64 K-tiles
#define BKB (BK * 2)              // K-tile byte stride in a row = 128 B
#define RSTRIDE ((size_t)64 * K_DIM * 2)  // 64-row staging-round stride (bytes)

typedef __bf16 bf16;
typedef __attribute__((ext_vector_type(4))) __bf16 bf16x4;
typedef __attribute__((ext_vector_type(8))) __bf16 bf16x8;
typedef __attribute__((ext_vector_type(4))) float f32x4;

// ---------------------------------------------------------------------------
// Prep: x fp32->bf16 ; w fp32->sign(w) bf16. (unchanged, verified)
// ---------------------------------------------------------------------------
__global__ __launch_bounds__(256) void prep_kernel(const float* __restrict__ x,
                                                   const float* __restrict__ w,
                                                   bf16* __restrict__ xb,
                                                   bf16* __restrict__ wb) {
    const int idx = blockIdx.x * 256 + threadIdx.x;   // 0 .. 4,194,303
    float4 xv = ((const float4*)x)[idx];
    bf16x4 xo;
    xo[0] = (bf16)xv.x; xo[1] = (bf16)xv.y; xo[2] = (bf16)xv.z; xo[3] = (bf16)xv.w;
    ((bf16x4*)xb)[idx] = xo;

    float4 wv = ((const float4*)w)[idx];
    bf16x4 wo;
    wo[0] = (bf16)((wv.x > 0.f) ? 1.f : ((wv.x < 0.f) ? -1.f : 0.f));
    wo[1] = (bf16)((wv.y > 0.f) ? 1.f : ((wv.y < 0.f) ? -1.f : 0.f));
    wo[2] = (bf16)((wv.z > 0.f) ? 1.f : ((wv.z < 0.f) ? -1.f : 0.f));
    wo[3] = (bf16)((wv.w > 0.f) ? 1.f : ((wv.w < 0.f) ? -1.f : 0.f));
    ((bf16x4*)wb)[idx] = wo;
}

// ---------------------------------------------------------------------------
// GEMM: 256x256 tile, 8 waves (2M x 4N), BK=64, 8-phase counted-vmcnt schedule.
// R3: B-FRAGS PREFETCHED ONE PHASE AHEAD (register double-buffered by tile
// parity, read at prev tile's ph3 top) -> kills the once-per-tile ph0 LDS
// "B-storm" (96 KB/CU burst, ~750 cyc, previously unhidden). A-frags revert
// to same-phase reads (4/wave/phase, hidden under barrier skew) to stay
// inside the 256-VGPR combined budget at 2 waves/SIMD.
//
// Staging rounds (1 global_load_lds/thread each, 64 rows = 8KB):
//   a0..a3 = A rows [0,64)[64,128)[128,192)[192,256); b0..b3 same for B.
// Stage-issue schedule during tile t (unchanged):
//   ph0: (t+1).a1,a3 -> buf^1 | ph1: (t+2).b0,b1 | ph2: (t+2).b2,b3
//   ph3: (t+2).a0,a2          (ph1..3 -> buf)
// vmcnt audit (steady state, FIFO oldest-first):
//   t.ph0 tail VMCNT8: 10 outstanding -> completes t.a1,a3
//     (needed by ph2/ph3 A-frag reads: rows 64..127 / 192..255)
//   t.ph2 tail VMCNT6: 12 outstanding -> completes t+1.b0..b3, t+1.a0, t+1.a2
//     (needed by t.ph3 B-next reads and t+1.ph0/ph1 A-frag reads)
// Each vmcnt is followed by the closing s_barrier -> group guarantee.
// Overwrite windows: every staged region is written >=1 barrier after its
// last LDS read, and consumer lgkm-retire precedes that barrier. B of tile t
// is only read from LDS at t-1.ph3 (registers thereafter), so t's ph1/ph2
// stages into the live buffer are safe.
// ---------------------------------------------------------------------------
__device__ __forceinline__ void load_lds16(const void* g, void* l) {
    __builtin_amdgcn_global_load_lds(
        (const __attribute__((address_space(1))) void*)g,
        (__attribute__((address_space(3))) void*)l, 16, 0, 0);
}

__global__ __launch_bounds__(512, 2) void gemm_bin_kernel(const bf16* __restrict__ A,
                                                          const bf16* __restrict__ Bw,
                                                          const float* __restrict__ bias,
                                                          float* __restrict__ C) {
    // Row = 64 bf16 = 128 B = 8 granules of 16 B. Granule g of row r lives at
    // slot s = g ^ (r&7)  (bank-conflict-free, verified scheme).
    __shared__ __align__(16) bf16 As[2][BM * BK];   // 2 x 32 KB
    __shared__ __align__(16) bf16 Bs[2][BM * BK];   // 2 x 32 KB

    const int tid  = threadIdx.x;
    const int lane = tid & 63;
    const int wave = tid >> 6;        // 0..7
    const int wm   = wave >> 2;       // 0..1 (M half)
    const int wn   = wave & 3;        // 0..3 (N quarter)

    const int tileM = blockIdx.y * BM;
    const int tileN = blockIdx.x * BN;

    // Staging: round r, wave stages rows r*64 + wave*8 + (lane>>3).
    // LDS dest is linear (chunk base + lane*16); source granule pre-swizzled:
    // q = (lane&7) ^ (lane>>3)  (since row&7 == lane>>3 for 8-aligned chunks).
    const int rowInC = lane >> 3;
    const int q_src  = (lane & 7) ^ rowInC;
    const char* aSrc = (const char*)A  + ((size_t)(tileM + wave * 8 + rowInC) * K_DIM + q_src * 8) * 2;
    const char* bSrc = (const char*)Bw + ((size_t)(tileN + wave * 8 + rowInC) * K_DIM + q_src * 8) * 2;

#define STAGE_A(B_, R_, KOFF_) load_lds16(aSrc + (size_t)(R_) * RSTRIDE + (KOFF_), \
                                          &As[B_][((R_) * 64 + wave * 8) * BK])
#define STAGE_B(B_, R_, KOFF_) load_lds16(bSrc + (size_t)(R_) * RSTRIDE + (KOFF_), \
                                          &Bs[B_][((R_) * 64 + wave * 8) * BK])

    f32x4 acc[8][4];
#pragma unroll
    for (int i = 0; i < 8; ++i)
#pragma unroll
        for (int j = 0; j < 4; ++j)
            acc[i][j] = (f32x4){0.f, 0.f, 0.f, 0.f};

    bf16x8 bfrA[4][2];   // B-frag set used by even K-tiles (filled at odd ph3)
    bf16x8 bfrB[4][2];   // B-frag set used by odd K-tiles (filled at even ph3)

    // Fragment reads: lane = qf*16 + l15; granule g = kk*4 + qf at row base+l15;
    // slot s = g ^ (l15&7) (row&7 == l15&7 since bases are 16-aligned).
    const int l15 = lane & 15;
    const int qf  = lane >> 4;
    const int fragRowA = wm * 128 + l15;
    const int fragRowB = wn * 64 + l15;
    const int s0 = (0 + qf) ^ (l15 & 7);   // kk=0
    const int s1 = (4 + qf) ^ (l15 & 7);   // kk=1

// Same-phase A-frag read for phase P_ (rows 2*P_*16 .. +31 within wm half).
#define PREF_AF(B_, P_) \
    _Pragma("unroll") \
    for (int ii = 0; ii < 2; ++ii) { \
        af[ii][0] = *(const bf16x8*)&As[B_][(fragRowA + (2 * (P_) + ii) * 16) * BK + s0 * 8]; \
        af[ii][1] = *(const bf16x8*)&As[B_][(fragRowA + (2 * (P_) + ii) * 16) * BK + s1 * 8]; \
    }

// Next-tile B-frag prefetch into register set DST_ from LDS buffer BSRC_.
#define READ_BN(DST_, BSRC_) \
    _Pragma("unroll") \
    for (int j = 0; j < 4; ++j) { \
        DST_[j][0] = *(const bf16x8*)&Bs[BSRC_][(fragRowB + j * 16) * BK + s0 * 8]; \
        DST_[j][1] = *(const bf16x8*)&Bs[BSRC_][(fragRowB + j * 16) * BK + s1 * 8]; \
    }

#define MFMA16(P_, BU_) \
    _Pragma("unroll") \
    for (int ii = 0; ii < 2; ++ii) \
        _Pragma("unroll") \
        for (int j = 0; j < 4; ++j) { \
            acc[2 * (P_) + ii][j] = __builtin_amdgcn_mfma_f32_16x16x32_bf16(af[ii][0], BU_[j][0], acc[2 * (P_) + ii][j], 0, 0, 0); \
            acc[2 * (P_) + ii][j] = __builtin_amdgcn_mfma_f32_16x16x32_bf16(af[ii][1], BU_[j][1], acc[2 * (P_) + ii][j], 0, 0, 0); \
        }

#define VMCNT8 asm volatile("s_waitcnt vmcnt(8)" ::: "memory")
#define VMCNT6 asm volatile("s_waitcnt vmcnt(6)" ::: "memory")
#define BAR    __builtin_amdgcn_s_barrier()
#define SCHED0 __builtin_amdgcn_sched_barrier(0)
#define PRIO1  __builtin_amdgcn_s_setprio(1)
#define PRIO0  __builtin_amdgcn_s_setprio(0)

    // KTILE(B_, BU_, BN_): compute tile in buf B_ using B-frag set BU_;
    // at ph3 prefetch next tile's B-frags from Bs[B_^1] into set BN_.
    // ph3 issue order pinned (af first, then B-next) so the compiler's
    // pre-MFMA(3) wait is lgkmcnt(8), not a full drain of the B-next reads.
#define KTILE(B_, BU_, BN_, K1_, K2_) do { \
        { bf16x8 af[2][2]; \
          PREF_AF(B_, 0); \
          STAGE_A((B_) ^ 1, 1, K1_); STAGE_A((B_) ^ 1, 3, K1_); \
          BAR; PRIO1; MFMA16(0, BU_); PRIO0; VMCNT8; BAR; SCHED0; } \
        { bf16x8 af[2][2]; \
          PREF_AF(B_, 1); \
          STAGE_B(B_, 0, K2_); STAGE_B(B_, 1, K2_); \
          BAR; PRIO1; MFMA16(1, BU_); PRIO0; BAR; SCHED0; } \
        { bf16x8 af[2][2]; \
          PREF_AF(B_, 2); \
          STAGE_B(B_, 2, K2_); STAGE_B(B_, 3, K2_); \
          BAR; PRIO1; MFMA16(2, BU_); PRIO0; VMCNT6; BAR; SCHED0; } \
        { bf16x8 af[2][2]; \
          PREF_AF(B_, 3); \
          SCHED0; \
          READ_BN(BN_, (B_) ^ 1); \
          STAGE_A(B_, 0, K2_); STAGE_A(B_, 2, K2_); \
          BAR; PRIO1; MFMA16(3, BU_); PRIO0; BAR; SCHED0; } \
    } while (0)

    // ---- prologue: tile0 fully, then tile1's {b0..b3,a0,a2} (steady-state
    // ---- FIFO order); prime bfrA with tile0's B-frags after the barrier ----
    STAGE_B(0, 0, 0);   STAGE_B(0, 1, 0);   STAGE_B(0, 2, 0);   STAGE_B(0, 3, 0);
    STAGE_A(0, 0, 0);   STAGE_A(0, 2, 0);   STAGE_A(0, 1, 0);   STAGE_A(0, 3, 0);
    STAGE_B(1, 0, BKB); STAGE_B(1, 1, BKB); STAGE_B(1, 2, BKB); STAGE_B(1, 3, BKB);
    STAGE_A(1, 0, BKB); STAGE_A(1, 2, BKB);
    VMCNT6;                                // tile0 landed; tile1 6-in-flight
    BAR;
    SCHED0;
    READ_BN(bfrA, 0);                      // prime tile0's B-frag set

    // ---- main loop: 2 K-tiles per iteration (static buffer/set parity) -----
    // Tail prefetches wrap K-offset to 0: harmless (regions/sets re-verified),
    // keeps the loop branch-free.
    for (int kt = 0; kt < NKT; kt += 2) {
        const int k1a = (kt + 1) * BKB;                               // tile kt+1
        const int k2a = (kt + 2 < NKT) ? (kt + 2) * BKB : 0;          // tile kt+2
        KTILE(0, bfrA, bfrB, k1a, k2a);
        const int k2b = (kt + 3 < NKT) ? (kt + 3) * BKB : 0;          // tile kt+3
        KTILE(1, bfrB, bfrA, k2a, k2b);
    }

    // ---- epilogue: C/D layout col = lane&15, row = (lane>>4)*4 + reg -------
#pragma unroll
    for (int j = 0; j < 4; ++j) {
        const int col = tileN + wn * 64 + j * 16 + l15;
        const float bv = bias[col];
#pragma unroll
        for (int i = 0; i < 8; ++i) {
            const int row0 = tileM + wm * 128 + i * 16 + (qf << 2);
#pragma unroll
            for (int rr = 0; rr < 4; ++rr) {
                C[(size_t)(row0 + rr) * N_DIM + col] = acc[i][j][rr] + bv;
            }
        }
    }

#undef STAGE_A
#undef STAGE_B
#undef PREF_AF
#undef READ_BN
#undef MFMA16
#undef VMCNT8
#undef VMCNT6
#undef BAR
#undef SCHED0
#undef PRIO1
#undef PRIO0
#undef KTILE
}

// ---------------------------------------------------------------------------
extern "C" void kernel_launch(void* const* d_in, const int* in_sizes, int n_in,
                              void* d_out, int out_size, void* d_ws, size_t ws_size,
                              hipStream_t stream) {
    const float* x    = (const float*)d_in[0];  // [M,K]
    const float* w    = (const float*)d_in[1];  // [N,K]
    const float* bias = (const float*)d_in[2];  // [N]
    float* out        = (float*)d_out;          // [M,N]

    const int nElem = M_DIM * K_DIM;
    bf16* xb = (bf16*)d_ws;
    bf16* wb = xb + (size_t)nElem;

    prep_kernel<<<nElem / 4 / 256, 256, 0, stream>>>(x, w, xb, wb);

    dim3 grid(N_DIM / BN, M_DIM / BM);          // 16 x 16 = 256 blocks = 1/CU
    gemm_bin_kernel<<<grid, 512, 0, stream>>>(xb, wb, bias, out);
}

// Round 4
// 285.828 us; speedup vs baseline: 1.0297x; 1.0297x over previous
//
#include <hip/hip_runtime.h>
#include <hip/hip_bf16.h>
#include <stdint.h>
#include <stddef.h>

// out[M,N] = X[M,K] @ sign(W[N,K])^T + bias[N];  M=N=K=4096, fp32 in/out.
#define M_DIM 4096
#define N_DIM 4096
#define K_DIM 4096
#define BM 256
#define BN 256
#define BK 64
#define NKT (K_DIM / BK)          // 64 K-tiles
#define BKB (BK * 2)              // K-tile byte stride in a row = 128 B
#define RSTRIDE ((size_t)64 * K_DIM * 2)  // 64-row staging-round stride (bytes)

typedef __bf16 bf16;
typedef __attribute__((ext_vector_type(4))) __bf16 bf16x4;
typedef __attribute__((ext_vector_type(8))) __bf16 bf16x8;
typedef __attribute__((ext_vector_type(4))) float f32x4;
typedef __attribute__((ext_vector_type(16))) float f32x16;

// ---------------------------------------------------------------------------
// Prep: x fp32->bf16 ; w fp32->sign(w) bf16. (unchanged, verified)
// ---------------------------------------------------------------------------
__global__ __launch_bounds__(256) void prep_kernel(const float* __restrict__ x,
                                                   const float* __restrict__ w,
                                                   bf16* __restrict__ xb,
                                                   bf16* __restrict__ wb) {
    const int idx = blockIdx.x * 256 + threadIdx.x;   // 0 .. 4,194,303
    float4 xv = ((const float4*)x)[idx];
    bf16x4 xo;
    xo[0] = (bf16)xv.x; xo[1] = (bf16)xv.y; xo[2] = (bf16)xv.z; xo[3] = (bf16)xv.w;
    ((bf16x4*)xb)[idx] = xo;

    float4 wv = ((const float4*)w)[idx];
    bf16x4 wo;
    wo[0] = (bf16)((wv.x > 0.f) ? 1.f : ((wv.x < 0.f) ? -1.f : 0.f));
    wo[1] = (bf16)((wv.y > 0.f) ? 1.f : ((wv.y < 0.f) ? -1.f : 0.f));
    wo[2] = (bf16)((wv.z > 0.f) ? 1.f : ((wv.z < 0.f) ? -1.f : 0.f));
    wo[3] = (bf16)((wv.w > 0.f) ? 1.f : ((wv.w < 0.f) ? -1.f : 0.f));
    ((bf16x4*)wb)[idx] = wo;
}

// ---------------------------------------------------------------------------
// GEMM R4: 256x256 tile, 8 waves (2M x 4N), BK=64.
// Change vs R1 (best, 132us): (a) MFMA shape 16x16x32 -> 32x32x16 (+15%
// matrix ceiling per ubench m06/m119, half the MFMA instruction count);
// (b) 4 phases/K-tile -> 2 phases/K-tile (4 barriers/tile instead of 8).
// Read placement reverted to R1 style (same-phase reads; R2/R3 prefetch
// experiments were null/negative).
//
// Per wave: output 128x64 = 4 Mfrag x 2 Nfrag of 32x32; 4 k-slices of 16.
//   phA: Mfrags 0,1 (16 MFMA) ; reads B-frags (8 x b128, reused all tile)
//        + A-frags Mfrag0,1 (8 x b128)
//   phB: Mfrags 2,3 (16 MFMA) ; reads A-frags Mfrag2,3 (8 x b128)
// Staging rounds (64 rows = 8KB each): a0..a3 / b0..b3 as before.
//   phA issues: (t+1).a1,a3 -> buf^1   [a1/a3 of buf^1 last read prev phB]
//   phB issues: (t+2).{b0..b3,a0,a2} -> buf [b*,a0,a2 last read this phA]
// vmcnt audit (steady, FIFO): entering t.phA in-flight = (t+1).{b*,a0,a2} [6].
//   +2 (phA) = 8; +6 (phB) = 14; VMCNT6 @ phB tail completes 8 oldest =
//   ALL of tile t+1, leaves (t+2)'s 6 -> invariant restored. Followed by
//   s_barrier -> group guarantee. One vmcnt per K-tile, never 0.
// ---------------------------------------------------------------------------
__device__ __forceinline__ void load_lds16(const void* g, void* l) {
    __builtin_amdgcn_global_load_lds(
        (const __attribute__((address_space(1))) void*)g,
        (__attribute__((address_space(3))) void*)l, 16, 0, 0);
}

__global__ __launch_bounds__(512, 2) void gemm_bin_kernel(const bf16* __restrict__ A,
                                                          const bf16* __restrict__ Bw,
                                                          const float* __restrict__ bias,
                                                          float* __restrict__ C) {
    // Row = 64 bf16 = 128 B = 8 granules of 16 B. Granule g of row r lives at
    // slot s = g ^ (r&7)  (bank-conflict-free; re-verified for the 32x32
    // fragment pattern: per 16-lane quarter, 2 rows/slot = 2-way = free).
    __shared__ __align__(16) bf16 As[2][BM * BK];   // 2 x 32 KB
    __shared__ __align__(16) bf16 Bs[2][BM * BK];   // 2 x 32 KB

    const int tid  = threadIdx.x;
    const int lane = tid & 63;
    const int wave = tid >> 6;        // 0..7
    const int wm   = wave >> 2;       // 0..1 (M half)
    const int wn   = wave & 3;        // 0..3 (N quarter)

    const int tileM = blockIdx.y * BM;
    const int tileN = blockIdx.x * BN;

    // Staging: round r, wave stages rows r*64 + wave*8 + (lane>>3).
    // LDS dest linear (chunk base + lane*16); source granule pre-swizzled:
    // q = (lane&7) ^ (lane>>3)  (row&7 == lane>>3 for 8-aligned chunks).
    const int rowInC = lane >> 3;
    const int q_src  = (lane & 7) ^ rowInC;
    const char* aSrc = (const char*)A  + ((size_t)(tileM + wave * 8 + rowInC) * K_DIM + q_src * 8) * 2;
    const char* bSrc = (const char*)Bw + ((size_t)(tileN + wave * 8 + rowInC) * K_DIM + q_src * 8) * 2;

#define STAGE_A(B_, R_, KOFF_) load_lds16(aSrc + (size_t)(R_) * RSTRIDE + (KOFF_), \
                                          &As[B_][((R_) * 64 + wave * 8) * BK])
#define STAGE_B(B_, R_, KOFF_) load_lds16(bSrc + (size_t)(R_) * RSTRIDE + (KOFF_), \
                                          &Bs[B_][((R_) * 64 + wave * 8) * BK])

    f32x16 acc[4][2];   // [Mfrag 32-row][Nfrag 32-col]
#pragma unroll
    for (int i = 0; i < 4; ++i)
#pragma unroll
        for (int j = 0; j < 2; ++j)
            acc[i][j] = (f32x16){0.f,0.f,0.f,0.f,0.f,0.f,0.f,0.f,
                                 0.f,0.f,0.f,0.f,0.f,0.f,0.f,0.f};

    bf16x8 bfr[2][4];   // B-frags [Nfrag][kslice], read at phA, reused at phB

    // 32x32x16 operand layout: lane l holds row/col (l&31), k-granule (l>>5)
    // (8 contiguous bf16 along k) -- analog of the verified 16x16x32 mapping.
    // For k-slice ks (k = ks*16): granule g = ks*2 + (l>>5);
    // swizzled slot = g ^ (row&7) = g ^ (l&7)  (row bases are 32-aligned).
    const int l31 = lane & 31;
    const int hi  = lane >> 5;
    const int sl7 = lane & 7;

#define ASLOT(KS_) ((((KS_) * 2 + hi) ^ sl7) * 8)

#define READ_A(B_, P_) \
    _Pragma("unroll") \
    for (int ii = 0; ii < 2; ++ii) \
        _Pragma("unroll") \
        for (int ks = 0; ks < 4; ++ks) \
            af[ii][ks] = *(const bf16x8*)&As[B_][(wm * 128 + (P_) * 64 + ii * 32 + l31) * BK + ASLOT(ks)];

#define READ_B(B_) \
    _Pragma("unroll") \
    for (int j = 0; j < 2; ++j) \
        _Pragma("unroll") \
        for (int ks = 0; ks < 4; ++ks) \
            bfr[j][ks] = *(const bf16x8*)&Bs[B_][(wn * 64 + j * 32 + l31) * BK + ASLOT(ks)];

#define MFMA32(P_) \
    _Pragma("unroll") \
    for (int ks = 0; ks < 4; ++ks) \
        _Pragma("unroll") \
        for (int ii = 0; ii < 2; ++ii) \
            _Pragma("unroll") \
            for (int j = 0; j < 2; ++j) \
                acc[2 * (P_) + ii][j] = __builtin_amdgcn_mfma_f32_32x32x16_bf16( \
                    af[ii][ks], bfr[j][ks], acc[2 * (P_) + ii][j], 0, 0, 0);

#define VMCNT6 asm volatile("s_waitcnt vmcnt(6)" ::: "memory")
#define BAR    __builtin_amdgcn_s_barrier()
#define SCHED0 __builtin_amdgcn_sched_barrier(0)
#define PRIO1  __builtin_amdgcn_s_setprio(1)
#define PRIO0  __builtin_amdgcn_s_setprio(0)

    // Overwrite-window ledger (all separations >= 1 barrier):
    //  phA stage (t+1).a1,a3 -> buf^1 : last read = prev tile phB top.
    //  phB stage (t+2).b*,a0,a2 -> buf: last read = this tile phA top.
#define KTILE(B_, K1_, K2_) do { \
        { bf16x8 af[2][4]; \
          READ_B(B_); \
          READ_A(B_, 0); \
          STAGE_A((B_) ^ 1, 1, K1_); STAGE_A((B_) ^ 1, 3, K1_); \
          BAR; PRIO1; MFMA32(0); PRIO0; BAR; SCHED0; } \
        { bf16x8 af[2][4]; \
          READ_A(B_, 1); \
          STAGE_B(B_, 0, K2_); STAGE_B(B_, 1, K2_); \
          STAGE_B(B_, 2, K2_); STAGE_B(B_, 3, K2_); \
          STAGE_A(B_, 0, K2_); STAGE_A(B_, 2, K2_); \
          BAR; PRIO1; MFMA32(1); PRIO0; VMCNT6; BAR; SCHED0; } \
    } while (0)

    // ---- prologue: tile0 fully, then tile1's {b0..b3,a0,a2}  --------------
    STAGE_B(0, 0, 0);   STAGE_B(0, 1, 0);   STAGE_B(0, 2, 0);   STAGE_B(0, 3, 0);
    STAGE_A(0, 0, 0);   STAGE_A(0, 2, 0);   STAGE_A(0, 1, 0);   STAGE_A(0, 3, 0);
    STAGE_B(1, 0, BKB); STAGE_B(1, 1, BKB); STAGE_B(1, 2, BKB); STAGE_B(1, 3, BKB);
    STAGE_A(1, 0, BKB); STAGE_A(1, 2, BKB);
    VMCNT6;                                // tile0 landed; tile1 6-in-flight
    BAR;
    SCHED0;

    // ---- main loop: 2 K-tiles per iteration (static buffer parity) ---------
    // Tail prefetches wrap K-offset to 0: they target regions of the buffer
    // not read after their issue point (same ledger as steady state) ->
    // harmless garbage, loop stays branch-free.
    for (int kt = 0; kt < NKT; kt += 2) {
        const int k1a = (kt + 1) * BKB;                               // tile kt+1
        const int k2a = (kt + 2 < NKT) ? (kt + 2) * BKB : 0;          // tile kt+2
        KTILE(0, k1a, k2a);
        const int k2b = (kt + 3 < NKT) ? (kt + 3) * BKB : 0;          // tile kt+3
        KTILE(1, k2a, k2b);
    }

    // ---- epilogue: 32x32 C/D layout (m74/m101-verified):
    //      col = lane&31, row = (reg&3) + 8*(reg>>2) + 4*(lane>>5) ----------
#pragma unroll
    for (int j = 0; j < 2; ++j) {
        const int col = tileN + wn * 64 + j * 32 + l31;
        const float bv = bias[col];
#pragma unroll
        for (int i = 0; i < 4; ++i) {
            const int rowBase = tileM + wm * 128 + i * 32 + hi * 4;
#pragma unroll
            for (int reg = 0; reg < 16; ++reg) {
                const int row = rowBase + (reg & 3) + 8 * (reg >> 2);
                C[(size_t)row * N_DIM + col] = acc[i][j][reg] + bv;
            }
        }
    }

#undef STAGE_A
#undef STAGE_B
#undef ASLOT
#undef READ_A
#undef READ_B
#undef MFMA32
#undef VMCNT6
#undef BAR
#undef SCHED0
#undef PRIO1
#undef PRIO0
#undef KTILE
}

// ---------------------------------------------------------------------------
extern "C" void kernel_launch(void* const* d_in, const int* in_sizes, int n_in,
                              void* d_out, int out_size, void* d_ws, size_t ws_size,
                              hipStream_t stream) {
    const float* x    = (const float*)d_in[0];  // [M,K]
    const float* w    = (const float*)d_in[1];  // [N,K]
    const float* bias = (const float*)d_in[2];  // [N]
    float* out        = (float*)d_out;          // [M,N]

    const int nElem = M_DIM * K_DIM;
    bf16* xb = (bf16*)d_ws;
    bf16* wb = xb + (size_t)nElem;

    prep_kernel<<<nElem / 4 / 256, 256, 0, stream>>>(x, w, xb, wb);

    dim3 grid(N_DIM / BN, M_DIM / BM);          // 16 x 16 = 256 blocks = 1/CU
    gemm_bin_kernel<<<grid, 512, 0, stream>>>(xb, wb, bias, out);
}